// Round 8
// baseline (100.675 us; speedup 1.0000x reference)
//
#include <hip/hip_runtime.h>
#include <math.h>

#define HID 512
#define IN_FEAT 342
#define OUTD 311
#define BATCH 256
#define KP0 352           // layer-0 padded K (11 chunks of 32)
#define XROW (IN_FEAT + 1)

// fragment geometry: chunk block = 1024 u16 (512 hi + 512 lo);
// element (plane, lane, j) at plane*512 + lane*8 + j; lane = q*16 + m holds
// W[s][ot*16+m][cc*32+q*8+j].
#define NT1 32
#define NCC1 16
#define NT2 20
#define NCC2 16
#define NCC0 11

typedef unsigned short u16;
typedef short bf16x8 __attribute__((ext_vector_type(8)));
typedef float f32x4 __attribute__((ext_vector_type(4)));

__device__ __forceinline__ u16 f2bf_rne(float v) {
    unsigned int x = __float_as_uint(v);
    unsigned int r = (x + 0x7fffu + ((x >> 16) & 1u)) >> 16;
    return (u16)r;
}
__device__ __forceinline__ float bf2f(u16 u) {
    return __uint_as_float(((unsigned int)u) << 16);
}

union U8 { u16 u[8]; uint4 v; };

__device__ __forceinline__ void split8(const float* __restrict__ src, bf16x8& hi, bf16x8& lo) {
#pragma unroll
    for (int j = 0; j < 8; j++) {
        u16 h = f2bf_rne(src[j]);
        hi[j] = (short)h;
        lo[j] = (short)f2bf_rne(src[j] - bf2f(h));
    }
}

// ================= L0 + prep fused =================
// Block (bx, by): computes out rows o0=by*16 for batches b0=bx*32 (all 4 slices,
// 8 waves = slice x b-half). W0 tile (4 slices x 16 rows x 342) is read row-major
// COALESCED f32 and fragment-scattered into LDS; K-loop is fully LDS-fed.
// Side job (blocks 0..207): convert one W1/W2 tile to global fragments F1/F2
// for the next kernels (read coalesced, 16B fragment stores).
#define NB0 32
#define KLDS0 360
__global__ __launch_bounds__(512, 1) void layer0_fused(
    const float* __restrict__ W0, const float* __restrict__ W1, const float* __restrict__ W2,
    const float* __restrict__ x, const float* __restrict__ bias,
    u16* __restrict__ F1, u16* __restrict__ F2,
    u16* __restrict__ Ohi, u16* __restrict__ Olo)
{
    __shared__ u16 wlds[4 * NCC0 * 1024];      // 90112 B: W0 fragments, 4 slices
    __shared__ u16 hlds[2 * NB0 * KLDS0];      // 46080 B: H hi/lo
    __shared__ float accs[4][NB0][17];         //  8704 B: blend buffer

    const int blk = (int)blockIdx.x;
    const int bx = (blk >> 3) & 7;
    const int by = (blk & 7) | ((blk >> 6) << 3);   // blk%8 == by%8: XCD weight locality
    const int tid = (int)threadIdx.x;
    const int b0 = bx * NB0;
    const int o0 = by * 16;

    // ---- stage W0 fragments (4 slices) into LDS: items (s, rr, c) = 4*16*44 ----
    for (int idx = tid; idx < 4 * 16 * 44; idx += 512) {
        int s = idx / (16 * 44);
        int rem = idx - s * (16 * 44);
        int rr = rem / 44, c = rem - rr * 44;
        int k = c * 8;
        const float* rp = W0 + (size_t)(s * 512 + o0 + rr) * IN_FEAT;
        float src[8];
        if (k + 8 <= IN_FEAT) {            // rows 8B-aligned: float2 loads
            const float2* p2 = reinterpret_cast<const float2*>(rp + k);
            float2 v0 = p2[0], v1 = p2[1], v2 = p2[2], v3 = p2[3];
            src[0] = v0.x; src[1] = v0.y; src[2] = v1.x; src[3] = v1.y;
            src[4] = v2.x; src[5] = v2.y; src[6] = v3.x; src[7] = v3.y;
        } else {
#pragma unroll
            for (int j = 0; j < 8; j++) src[j] = (k + j < IN_FEAT) ? rp[k + j] : 0.f;
        }
        U8 hi, lo;
#pragma unroll
        for (int j = 0; j < 8; j++) {
            u16 h = f2bf_rne(src[j]);
            hi.u[j] = h;
            lo.u[j] = f2bf_rne(src[j] - bf2f(h));
        }
        int cc = c >> 2, lane = (c & 3) * 16 + rr;
        *reinterpret_cast<uint4*>(&wlds[(s * NCC0 + cc) * 1024 + lane * 8])       = hi.v;
        *reinterpret_cast<uint4*>(&wlds[(s * NCC0 + cc) * 1024 + 512 + lane * 8]) = lo.v;
    }

    // ---- stage H tile from x (convert during staging): items 32*44 ----
    for (int idx = tid; idx < NB0 * 44; idx += 512) {
        int r = idx / 44, c = idx - r * 44;
        int k = c * 8;
        const float* xr = x + (size_t)(b0 + r) * XROW;
        float src[8];
#pragma unroll
        for (int j = 0; j < 8; j++) {
            int kk = k + j;
            src[j] = (kk < IN_FEAT) ? xr[kk] : 0.f;
        }
        bf16x8 hi, lo;
        split8(src, hi, lo);
        *reinterpret_cast<bf16x8*>(&hlds[r * KLDS0 + k])                 = hi;
        *reinterpret_cast<bf16x8*>(&hlds[NB0 * KLDS0 + r * KLDS0 + k])   = lo;
    }
    __syncthreads();

    const int lane = tid & 63;
    const int w = tid >> 6;
    const int s = w & 3;                      // slice
    const int t = w >> 2;                     // b-half
    const int m = lane & 15;
    const int q = lane >> 4;

    const u16* wf  = &wlds[s * NCC0 * 1024 + lane * 8];
    const u16* hp  = &hlds[(t * 16 + m) * KLDS0 + q * 8];
    const u16* hpl = &hlds[NB0 * KLDS0 + (t * 16 + m) * KLDS0 + q * 8];

    // inline cubic blend coefficient d_s(b)
    const int brow = b0 + t * 16 + m;
    const float ps = 4.f * x[(size_t)brow * XROW + IN_FEAT];
    const float fl = floorf(ps);
    const float mu = ps - fl;
    const int i1 = ((int)fl) & 3;
    const int jj = (s - i1) & 3;
    const float mu2 = mu * mu, mu3 = mu2 * mu;
    const float ds = (jj == 0) ? ( 1.5f * mu3 - 2.5f * mu2 + 1.0f)
                   : (jj == 1) ? (-1.5f * mu3 + 2.0f * mu2 + 0.5f * mu)
                   : (jj == 2) ? ( 0.5f * mu3 - 0.5f * mu2)
                   :             (-0.5f * mu3 + mu2 - 0.5f * mu);

    f32x4 a0 = {0.f, 0.f, 0.f, 0.f};
    f32x4 a1 = {0.f, 0.f, 0.f, 0.f};
    f32x4 a2 = {0.f, 0.f, 0.f, 0.f};
#pragma unroll
    for (int cc = 0; cc < NCC0; ++cc) {
        bf16x8 ah = *reinterpret_cast<const bf16x8*>(wf + cc * 1024);
        bf16x8 al = *reinterpret_cast<const bf16x8*>(wf + cc * 1024 + 512);
        bf16x8 bh = *reinterpret_cast<const bf16x8*>(hp + cc * 32);
        bf16x8 bl = *reinterpret_cast<const bf16x8*>(hpl + cc * 32);
        a0 = __builtin_amdgcn_mfma_f32_16x16x32_bf16(ah, bh, a0, 0, 0, 0);
        a1 = __builtin_amdgcn_mfma_f32_16x16x32_bf16(ah, bl, a1, 0, 0, 0);
        a2 = __builtin_amdgcn_mfma_f32_16x16x32_bf16(al, bh, a2, 0, 0, 0);
    }
    __syncthreads();

    f32x4 sum = a0 + a1 + a2;
#pragma unroll
    for (int r = 0; r < 4; ++r) {
        int o = o0 + q * 4 + r;
        accs[s][t * 16 + m][q * 4 + r] = ds * (sum[r] + bias[(size_t)s * HID + o]);
    }
    __syncthreads();

    const int b_l = tid >> 4;
    const int o_l = tid & 15;
    float vv = accs[0][b_l][o_l] + accs[1][b_l][o_l]
             + accs[2][b_l][o_l] + accs[3][b_l][o_l];
    {
        float e = (vv > 0.f) ? vv : expm1f(vv);
        u16 h = f2bf_rne(e);
        const int o = o0 + o_l;
        const int b = b0 + b_l;
        Ohi[(size_t)b * HID + o] = h;
        Olo[(size_t)b * HID + o] = f2bf_rne(e - bf2f(h));
    }

    // ---- side job: build F1 (blocks 0..127) / F2 (blocks 128..207) ----
    if (blk < 208) {
        const bool w2j = (blk >= 128);
        int l = w2j ? (blk - 128) : blk;
        int js, jot;
        if (w2j) { js = l / 20; jot = l - js * 20; }
        else     { js = l >> 5; jot = l & 31; }
        u16* Fd = w2j ? (F2 + (size_t)(js * NT2 + jot) * NCC2 * 1024)
                      : (F1 + (size_t)(js * NT1 + jot) * NCC1 * 1024);
        for (int idx = tid; idx < 16 * 64; idx += 512) {
            int rr = idx >> 6, c = idx & 63;
            float src[8] = {0.f, 0.f, 0.f, 0.f, 0.f, 0.f, 0.f, 0.f};
            if (!w2j) {
                const float4* p4 = reinterpret_cast<const float4*>(
                    W1 + (size_t)(js * 512 + jot * 16 + rr) * 512 + c * 8);
                float4 v0 = p4[0], v1 = p4[1];
                src[0] = v0.x; src[1] = v0.y; src[2] = v0.z; src[3] = v0.w;
                src[4] = v1.x; src[5] = v1.y; src[6] = v1.z; src[7] = v1.w;
            } else {
                int orow = jot * 16 + rr;
                if (orow < OUTD) {
                    const float4* p4 = reinterpret_cast<const float4*>(
                        W2 + ((size_t)js * OUTD + orow) * 512 + c * 8);
                    float4 v0 = p4[0], v1 = p4[1];
                    src[0] = v0.x; src[1] = v0.y; src[2] = v0.z; src[3] = v0.w;
                    src[4] = v1.x; src[5] = v1.y; src[6] = v1.z; src[7] = v1.w;
                }
            }
            U8 hi, lo;
#pragma unroll
            for (int j = 0; j < 8; j++) {
                u16 h = f2bf_rne(src[j]);
                hi.u[j] = h;
                lo.u[j] = f2bf_rne(src[j] - bf2f(h));
            }
            int cc = c >> 2, jl = (c & 3) * 16 + rr;
            *reinterpret_cast<uint4*>(Fd + cc * 1024 + jl * 8)       = hi.v;
            *reinterpret_cast<uint4*>(Fd + cc * 1024 + 512 + jl * 8) = lo.v;
        }
    }
}

// ===== L1/L2: NB=16, 256 thr, 4 waves (wave = slice), fragment weights (R7 verbatim) =====
#define NB 16
#define NTHR 256
template<int KP, int KLDS, int FINAL, int NT, int NBY>
__global__ __launch_bounds__(NTHR, 4) void layer_frag(
    const u16* __restrict__ Wf, const float* __restrict__ x,
    const u16* __restrict__ Hhi, const u16* __restrict__ Hlo,
    const float* __restrict__ bias, int Mb,
    u16* __restrict__ Ohi, u16* __restrict__ Olo, float* __restrict__ outp)
{
    union SharedU {
        u16 h[2][NB * KLDS];
        float acc[4][NB][17];
    };
    __shared__ SharedU sm;

    const int blk = (int)blockIdx.x;
    const int bx = (blk >> 3) & 15;
    const int by = (blk & 7) | ((blk >> 7) << 3);
    if (by >= NBY) return;

    const int tid = (int)threadIdx.x;
    const int b0 = bx * NB;
    const int o0 = by * 16;

    constexpr int CH = KP / 8;
    for (int idx = tid; idx < NB * CH; idx += NTHR) {
        int r = idx / CH, c = idx - r * CH;
        size_t g = (size_t)(b0 + r) * KP + c * 8;
        *reinterpret_cast<uint4*>(&sm.h[0][r * KLDS + c * 8]) =
            *reinterpret_cast<const uint4*>(Hhi + g);
        *reinterpret_cast<uint4*>(&sm.h[1][r * KLDS + c * 8]) =
            *reinterpret_cast<const uint4*>(Hlo + g);
    }
    __syncthreads();

    const int lane = tid & 63;
    const int s = tid >> 6;                   // wave = slice
    const int m = lane & 15;
    const int q = lane >> 4;

    constexpr int NCC = KP / 32;
    const u16* wf = Wf + ((size_t)(s * NT + by) * NCC) * 1024 + lane * 8;
    const u16* hp  = &sm.h[0][m * KLDS + q * 8];
    const u16* hpl = &sm.h[1][m * KLDS + q * 8];

    const int brow = b0 + m;
    const float ps = 4.f * x[(size_t)brow * XROW + IN_FEAT];
    const float fl = floorf(ps);
    const float mu = ps - fl;
    const int i1 = ((int)fl) & 3;
    const int jj = (s - i1) & 3;
    const float mu2 = mu * mu, mu3 = mu2 * mu;
    const float ds = (jj == 0) ? ( 1.5f * mu3 - 2.5f * mu2 + 1.0f)
                   : (jj == 1) ? (-1.5f * mu3 + 2.0f * mu2 + 0.5f * mu)
                   : (jj == 2) ? ( 0.5f * mu3 - 0.5f * mu2)
                   :             (-0.5f * mu3 + mu2 - 0.5f * mu);

    f32x4 a0 = {0.f, 0.f, 0.f, 0.f};
    f32x4 a1 = {0.f, 0.f, 0.f, 0.f};
    f32x4 a2 = {0.f, 0.f, 0.f, 0.f};
#pragma unroll
    for (int cc = 0; cc < NCC; ++cc) {
        bf16x8 ah = *reinterpret_cast<const bf16x8*>(wf + cc * 1024);
        bf16x8 al = *reinterpret_cast<const bf16x8*>(wf + cc * 1024 + 512);
        bf16x8 bh = *reinterpret_cast<const bf16x8*>(hp + cc * 32);
        bf16x8 bl = *reinterpret_cast<const bf16x8*>(hpl + cc * 32);
        a0 = __builtin_amdgcn_mfma_f32_16x16x32_bf16(ah, bh, a0, 0, 0, 0);
        a1 = __builtin_amdgcn_mfma_f32_16x16x32_bf16(ah, bl, a1, 0, 0, 0);
        a2 = __builtin_amdgcn_mfma_f32_16x16x32_bf16(al, bh, a2, 0, 0, 0);
    }
    __syncthreads();

    f32x4 sum = a0 + a1 + a2;
#pragma unroll
    for (int r = 0; r < 4; ++r) {
        int o = o0 + q * 4 + r;
        float bb = (o < Mb) ? bias[(size_t)s * Mb + o] : 0.f;
        sm.acc[s][m][q * 4 + r] = ds * (sum[r] + bb);
    }
    __syncthreads();

    const int b_l = tid >> 4;
    const int o_l = tid & 15;
    float vv = sm.acc[0][b_l][o_l] + sm.acc[1][b_l][o_l]
             + sm.acc[2][b_l][o_l] + sm.acc[3][b_l][o_l];
    const int o = o0 + o_l;
    const int b = b0 + b_l;
    if (!FINAL) {
        float e = (vv > 0.f) ? vv : expm1f(vv);
        u16 h = f2bf_rne(e);
        Ohi[(size_t)b * HID + o] = h;
        Olo[(size_t)b * HID + o] = f2bf_rne(e - bf2f(h));
    } else if (o < OUTD) {
        outp[(size_t)b * OUTD + o] = vv;
    }
}

extern "C" void kernel_launch(void* const* d_in, const int* in_sizes, int n_in,
                              void* d_out, int out_size, void* d_ws, size_t ws_size,
                              hipStream_t stream) {
    const float* x  = (const float*)d_in[0];
    const float* W0 = (const float*)d_in[1];
    const float* b0v = (const float*)d_in[2];
    const float* W1 = (const float*)d_in[3];
    const float* b1v = (const float*)d_in[4];
    const float* W2 = (const float*)d_in[5];
    const float* b2v = (const float*)d_in[6];
    float* out = (float*)d_out;

    char* pw = (char*)d_ws;
    auto alloc = [&](size_t bytes) { char* r = pw; pw += (bytes + 255) & ~(size_t)255; return r; };

    u16* F1 = (u16*)alloc((size_t)4 * NT1 * NCC1 * 1024 * 2);
    u16* F2 = (u16*)alloc((size_t)4 * NT2 * NCC2 * 1024 * 2);
    u16* hahi = (u16*)alloc((size_t)BATCH * HID * 2);
    u16* halo = (u16*)alloc((size_t)BATCH * HID * 2);
    u16* hbhi = (u16*)alloc((size_t)BATCH * HID * 2);
    u16* hblo = (u16*)alloc((size_t)BATCH * HID * 2);

    // L0 (+ W1/W2 fragment prep side job): 256 blocks x 512 thr
    layer0_fused<<<256, 512, 0, stream>>>(
        W0, W1, W2, x, b0v, F1, F2, hahi, halo);

    // L1: K=512, M=512 -> 512 blocks x 256 thr
    layer_frag<HID, 520, 0, NT1, 32><<<512, NTHR, 0, stream>>>(
        F1, x, hahi, halo, b1v, HID, hbhi, hblo, nullptr);

    // L2: K=512, M=311 (20 o-tiles) -> 384-block padded grid (320 active)
    layer_frag<HID, 520, 1, NT2, 20><<<384, NTHR, 0, stream>>>(
        F2, x, hbhi, hblo, b2v, OUTD, nullptr, nullptr, out);
}

// Round 9
// 99.993 us; speedup vs baseline: 1.0068x; 1.0068x over previous
//
#include <hip/hip_runtime.h>
#include <math.h>

#define HID 512
#define IN_FEAT 342
#define OUTD 311
#define BATCH 256
#define XROW (IN_FEAT + 1)

// fragment geometry: chunk block = 1024 u16 (512 hi + 512 lo);
// element (plane, lane, j) at plane*512 + lane*8 + j; lane = q*16 + m holds
// W[s][ot*16+m][cc*32+q*8+j].
#define NT1 32
#define NCC1 16
#define NT2 20
#define NCC2 16
#define NCC0 11

typedef unsigned short u16;
typedef short bf16x8 __attribute__((ext_vector_type(8)));
typedef float f32x4 __attribute__((ext_vector_type(4)));

__device__ __forceinline__ u16 f2bf_rne(float v) {
    unsigned int x = __float_as_uint(v);
    unsigned int r = (x + 0x7fffu + ((x >> 16) & 1u)) >> 16;
    return (u16)r;
}
__device__ __forceinline__ float bf2f(u16 u) {
    return __uint_as_float(((unsigned int)u) << 16);
}

union U8 { u16 u[8]; uint4 v; };

__device__ __forceinline__ void split8(const float* __restrict__ src, bf16x8& hi, bf16x8& lo) {
#pragma unroll
    for (int j = 0; j < 8; j++) {
        u16 h = f2bf_rne(src[j]);
        hi[j] = (short)h;
        lo[j] = (short)f2bf_rne(src[j] - bf2f(h));
    }
}

// ================= L0 + prep fused (R8 structure, f32 output) =================
// 8 waves = (slice, b-half). W0 tile fragment-staged in LDS (coalesced f32 reads);
// K-loop fully LDS-fed. Output: ACTIVATED f32 H0act (split8 moves to L1 staging —
// bit-identical values). Side jobs: blocks 0..207 build F1/F2 fragments;
// blocks 208..255 zero the f32 accumulators (H2acc, out) for split-K atomics.
#define NB0 32
#define KLDS0 360
__global__ __launch_bounds__(512, 1) void layer0_fused(
    const float* __restrict__ W0, const float* __restrict__ W1, const float* __restrict__ W2,
    const float* __restrict__ x, const float* __restrict__ bias,
    u16* __restrict__ F1, u16* __restrict__ F2,
    float* __restrict__ Oact, float* __restrict__ H2acc, float* __restrict__ outz)
{
    __shared__ u16 wlds[4 * NCC0 * 1024];      // 90112 B: W0 fragments, 4 slices
    __shared__ u16 hlds[2 * NB0 * KLDS0];      // 46080 B: H hi/lo
    __shared__ float accs[4][NB0][17];         //  8704 B: blend buffer

    const int blk = (int)blockIdx.x;
    const int bx = (blk >> 3) & 7;
    const int by = (blk & 7) | ((blk >> 6) << 3);   // blk%8 == by%8: XCD weight locality
    const int tid = (int)threadIdx.x;
    const int b0 = bx * NB0;
    const int o0 = by * 16;

    // ---- stage W0 fragments (4 slices) into LDS ----
    for (int idx = tid; idx < 4 * 16 * 44; idx += 512) {
        int s = idx / (16 * 44);
        int rem = idx - s * (16 * 44);
        int rr = rem / 44, c = rem - rr * 44;
        int k = c * 8;
        const float* rp = W0 + (size_t)(s * 512 + o0 + rr) * IN_FEAT;
        float src[8];
        if (k + 8 <= IN_FEAT) {            // rows 8B-aligned: float2 loads
            const float2* p2 = reinterpret_cast<const float2*>(rp + k);
            float2 v0 = p2[0], v1 = p2[1], v2 = p2[2], v3 = p2[3];
            src[0] = v0.x; src[1] = v0.y; src[2] = v1.x; src[3] = v1.y;
            src[4] = v2.x; src[5] = v2.y; src[6] = v3.x; src[7] = v3.y;
        } else {
#pragma unroll
            for (int j = 0; j < 8; j++) src[j] = (k + j < IN_FEAT) ? rp[k + j] : 0.f;
        }
        U8 hi, lo;
#pragma unroll
        for (int j = 0; j < 8; j++) {
            u16 h = f2bf_rne(src[j]);
            hi.u[j] = h;
            lo.u[j] = f2bf_rne(src[j] - bf2f(h));
        }
        int cc = c >> 2, lane = (c & 3) * 16 + rr;
        *reinterpret_cast<uint4*>(&wlds[(s * NCC0 + cc) * 1024 + lane * 8])       = hi.v;
        *reinterpret_cast<uint4*>(&wlds[(s * NCC0 + cc) * 1024 + 512 + lane * 8]) = lo.v;
    }

    // ---- stage H tile from x (convert during staging) ----
    for (int idx = tid; idx < NB0 * 44; idx += 512) {
        int r = idx / 44, c = idx - r * 44;
        int k = c * 8;
        const float* xr = x + (size_t)(b0 + r) * XROW;
        float src[8];
#pragma unroll
        for (int j = 0; j < 8; j++) {
            int kk = k + j;
            src[j] = (kk < IN_FEAT) ? xr[kk] : 0.f;
        }
        bf16x8 hi, lo;
        split8(src, hi, lo);
        *reinterpret_cast<bf16x8*>(&hlds[r * KLDS0 + k])               = hi;
        *reinterpret_cast<bf16x8*>(&hlds[NB0 * KLDS0 + r * KLDS0 + k]) = lo;
    }
    __syncthreads();

    const int lane = tid & 63;
    const int w = tid >> 6;
    const int s = w & 3;
    const int t = w >> 2;
    const int m = lane & 15;
    const int q = lane >> 4;

    const u16* wf  = &wlds[s * NCC0 * 1024 + lane * 8];
    const u16* hp  = &hlds[(t * 16 + m) * KLDS0 + q * 8];
    const u16* hpl = &hlds[NB0 * KLDS0 + (t * 16 + m) * KLDS0 + q * 8];

    const int brow = b0 + t * 16 + m;
    const float ps = 4.f * x[(size_t)brow * XROW + IN_FEAT];
    const float fl = floorf(ps);
    const float mu = ps - fl;
    const int i1 = ((int)fl) & 3;
    const int jj = (s - i1) & 3;
    const float mu2 = mu * mu, mu3 = mu2 * mu;
    const float ds = (jj == 0) ? ( 1.5f * mu3 - 2.5f * mu2 + 1.0f)
                   : (jj == 1) ? (-1.5f * mu3 + 2.0f * mu2 + 0.5f * mu)
                   : (jj == 2) ? ( 0.5f * mu3 - 0.5f * mu2)
                   :             (-0.5f * mu3 + mu2 - 0.5f * mu);

    f32x4 a0 = {0.f, 0.f, 0.f, 0.f};
    f32x4 a1 = {0.f, 0.f, 0.f, 0.f};
    f32x4 a2 = {0.f, 0.f, 0.f, 0.f};
#pragma unroll
    for (int cc = 0; cc < NCC0; ++cc) {
        bf16x8 ah = *reinterpret_cast<const bf16x8*>(wf + cc * 1024);
        bf16x8 al = *reinterpret_cast<const bf16x8*>(wf + cc * 1024 + 512);
        bf16x8 bh = *reinterpret_cast<const bf16x8*>(hp + cc * 32);
        bf16x8 bl = *reinterpret_cast<const bf16x8*>(hpl + cc * 32);
        a0 = __builtin_amdgcn_mfma_f32_16x16x32_bf16(ah, bh, a0, 0, 0, 0);
        a1 = __builtin_amdgcn_mfma_f32_16x16x32_bf16(ah, bl, a1, 0, 0, 0);
        a2 = __builtin_amdgcn_mfma_f32_16x16x32_bf16(al, bh, a2, 0, 0, 0);
    }
    __syncthreads();

    f32x4 sum = a0 + a1 + a2;
#pragma unroll
    for (int r = 0; r < 4; ++r) {
        int o = o0 + q * 4 + r;
        accs[s][t * 16 + m][q * 4 + r] = ds * (sum[r] + bias[(size_t)s * HID + o]);
    }
    __syncthreads();

    const int b_l = tid >> 4;
    const int o_l = tid & 15;
    float vv = accs[0][b_l][o_l] + accs[1][b_l][o_l]
             + accs[2][b_l][o_l] + accs[3][b_l][o_l];
    {
        float e = (vv > 0.f) ? vv : expm1f(vv);
        Oact[(size_t)(b0 + b_l) * HID + o0 + o_l] = e;   // activated f32
    }

    // ---- side job A: build F1 (blocks 0..127) / F2 (blocks 128..207) ----
    if (blk < 208) {
        const bool w2j = (blk >= 128);
        int l = w2j ? (blk - 128) : blk;
        int js, jot;
        if (w2j) { js = l / 20; jot = l - js * 20; }
        else     { js = l >> 5; jot = l & 31; }
        u16* Fd = w2j ? (F2 + (size_t)(js * NT2 + jot) * NCC2 * 1024)
                      : (F1 + (size_t)(js * NT1 + jot) * NCC1 * 1024);
        for (int idx = tid; idx < 16 * 64; idx += 512) {
            int rr = idx >> 6, c = idx & 63;
            float src[8] = {0.f, 0.f, 0.f, 0.f, 0.f, 0.f, 0.f, 0.f};
            if (!w2j) {
                const float4* p4 = reinterpret_cast<const float4*>(
                    W1 + (size_t)(js * 512 + jot * 16 + rr) * 512 + c * 8);
                float4 v0 = p4[0], v1 = p4[1];
                src[0] = v0.x; src[1] = v0.y; src[2] = v0.z; src[3] = v0.w;
                src[4] = v1.x; src[5] = v1.y; src[6] = v1.z; src[7] = v1.w;
            } else {
                int orow = jot * 16 + rr;
                if (orow < OUTD) {
                    const float4* p4 = reinterpret_cast<const float4*>(
                        W2 + ((size_t)js * OUTD + orow) * 512 + c * 8);
                    float4 v0 = p4[0], v1 = p4[1];
                    src[0] = v0.x; src[1] = v0.y; src[2] = v0.z; src[3] = v0.w;
                    src[4] = v1.x; src[5] = v1.y; src[6] = v1.z; src[7] = v1.w;
                }
            }
            U8 hi, lo;
#pragma unroll
            for (int j = 0; j < 8; j++) {
                u16 h = f2bf_rne(src[j]);
                hi.u[j] = h;
                lo.u[j] = f2bf_rne(src[j] - bf2f(h));
            }
            int cc = c >> 2, jl = (c & 3) * 16 + rr;
            *reinterpret_cast<uint4*>(Fd + cc * 1024 + jl * 8)       = hi.v;
            *reinterpret_cast<uint4*>(Fd + cc * 1024 + 512 + jl * 8) = lo.v;
        }
    } else {
        // ---- side job B: zero split-K accumulators (H2acc 131072 + out 79616 f32) ----
        for (int i = (blk - 208) * 512 + tid; i < 131072 + 79616; i += 48 * 512) {
            if (i < 131072) H2acc[i] = 0.f;
            else            outz[i - 131072] = 0.f;
        }
    }
}

// ===== L1/L2: split-K halves, NB=16, 256 thr, 4 waves; 4 blocks/CU = 16 waves/CU =====
// Block (bx, by, kh): half-K partial of out[b0..b0+15][o0..o0+15], all 4 slices
// reduced in LDS, then ONE f32 atomicAdd per output into a zero-init accumulator.
// Deterministic: acc starts at exactly 0; fl(p0+p1) is commutative.
// Decode: blk = (by&7) + 8*bx + 128*kh + 256*(by>>3) -> blk%8 == by%8 (XCD locality).
// ACT: apply ELU while staging Hin (L2 reads pre-activation accumulator).
#define KLDS1 264
template<int FINAL, int ACT, int NT, int NBY>
__global__ __launch_bounds__(256, 4) void layer_ks(
    const u16* __restrict__ Wf, const float* __restrict__ x,
    const float* __restrict__ Hin, const float* __restrict__ bias, int Mb,
    float* __restrict__ accout)
{
    union SharedU {
        u16 h[2][16 * KLDS1];
        float acc[4][16][17];
    };
    __shared__ SharedU sm;

    const int blk = (int)blockIdx.x;
    const int bx = (blk >> 3) & 15;
    const int kh = (blk >> 7) & 1;
    const int by = (blk & 7) | ((blk >> 8) << 3);
    if (by >= NBY) return;

    const int tid = (int)threadIdx.x;
    const int b0 = bx * 16;
    const int o0 = by * 16;

    // ---- stage H half-tile (16 rows x 256) from f32, split during staging ----
    for (int idx = tid; idx < 16 * 32; idx += 256) {
        int r = idx >> 5, c = idx & 31;
        const float4* hv = reinterpret_cast<const float4*>(
            Hin + (size_t)(b0 + r) * HID + kh * 256 + c * 8);
        float4 v0 = hv[0], v1 = hv[1];
        float src[8] = {v0.x, v0.y, v0.z, v0.w, v1.x, v1.y, v1.z, v1.w};
        if (ACT) {
#pragma unroll
            for (int j = 0; j < 8; j++) src[j] = (src[j] > 0.f) ? src[j] : expm1f(src[j]);
        }
        bf16x8 hi, lo;
        split8(src, hi, lo);
        *reinterpret_cast<bf16x8*>(&sm.h[0][r * KLDS1 + c * 8]) = hi;
        *reinterpret_cast<bf16x8*>(&sm.h[1][r * KLDS1 + c * 8]) = lo;
    }
    __syncthreads();

    const int lane = tid & 63;
    const int s = tid >> 6;                   // wave = slice
    const int m = lane & 15;
    const int q = lane >> 4;

    const u16* wf = Wf + ((size_t)(s * NT + by) * 16 + kh * 8) * 1024 + lane * 8;
    const u16* hp  = &sm.h[0][m * KLDS1 + q * 8];
    const u16* hpl = &sm.h[1][m * KLDS1 + q * 8];

    const int brow = b0 + m;
    const float ps = 4.f * x[(size_t)brow * XROW + IN_FEAT];
    const float fl = floorf(ps);
    const float mu = ps - fl;
    const int i1 = ((int)fl) & 3;
    const int jj = (s - i1) & 3;
    const float mu2 = mu * mu, mu3 = mu2 * mu;
    const float ds = (jj == 0) ? ( 1.5f * mu3 - 2.5f * mu2 + 1.0f)
                   : (jj == 1) ? (-1.5f * mu3 + 2.0f * mu2 + 0.5f * mu)
                   : (jj == 2) ? ( 0.5f * mu3 - 0.5f * mu2)
                   :             (-0.5f * mu3 + mu2 - 0.5f * mu);

    f32x4 a0 = {0.f, 0.f, 0.f, 0.f};
    f32x4 a1 = {0.f, 0.f, 0.f, 0.f};
    f32x4 a2 = {0.f, 0.f, 0.f, 0.f};
#pragma unroll
    for (int cc = 0; cc < 8; ++cc) {
        bf16x8 ah = *reinterpret_cast<const bf16x8*>(wf + cc * 1024);
        bf16x8 al = *reinterpret_cast<const bf16x8*>(wf + cc * 1024 + 512);
        bf16x8 bh = *reinterpret_cast<const bf16x8*>(hp + cc * 32);
        bf16x8 bl = *reinterpret_cast<const bf16x8*>(hpl + cc * 32);
        a0 = __builtin_amdgcn_mfma_f32_16x16x32_bf16(ah, bh, a0, 0, 0, 0);
        a1 = __builtin_amdgcn_mfma_f32_16x16x32_bf16(ah, bl, a1, 0, 0, 0);
        a2 = __builtin_amdgcn_mfma_f32_16x16x32_bf16(al, bh, a2, 0, 0, 0);
    }
    __syncthreads();

    f32x4 sum = a0 + a1 + a2;
#pragma unroll
    for (int r = 0; r < 4; ++r) {
        int o = o0 + q * 4 + r;
        float bb = (kh == 0 && o < Mb) ? bias[(size_t)s * Mb + o] : 0.f;
        sm.acc[s][m][q * 4 + r] = ds * (sum[r] + bb);
    }
    __syncthreads();

    const int b_l = tid >> 4;
    const int o_l = tid & 15;
    float vv = sm.acc[0][b_l][o_l] + sm.acc[1][b_l][o_l]
             + sm.acc[2][b_l][o_l] + sm.acc[3][b_l][o_l];
    const int o = o0 + o_l;
    const int b = b0 + b_l;
    if (FINAL) {
        if (o < OUTD) unsafeAtomicAdd(&accout[(size_t)b * OUTD + o], vv);
    } else {
        unsafeAtomicAdd(&accout[(size_t)b * HID + o], vv);
    }
}

extern "C" void kernel_launch(void* const* d_in, const int* in_sizes, int n_in,
                              void* d_out, int out_size, void* d_ws, size_t ws_size,
                              hipStream_t stream) {
    const float* x  = (const float*)d_in[0];
    const float* W0 = (const float*)d_in[1];
    const float* b0v = (const float*)d_in[2];
    const float* W1 = (const float*)d_in[3];
    const float* b1v = (const float*)d_in[4];
    const float* W2 = (const float*)d_in[5];
    const float* b2v = (const float*)d_in[6];
    float* out = (float*)d_out;

    char* pw = (char*)d_ws;
    auto alloc = [&](size_t bytes) { char* r = pw; pw += (bytes + 255) & ~(size_t)255; return r; };

    u16* F1 = (u16*)alloc((size_t)4 * NT1 * NCC1 * 1024 * 2);
    u16* F2 = (u16*)alloc((size_t)4 * NT2 * NCC2 * 1024 * 2);
    float* H0act = (float*)alloc((size_t)BATCH * HID * 4);
    float* H2acc = (float*)alloc((size_t)BATCH * HID * 4);

    // L0 (+ F1/F2 prep + accumulator zeroing): 256 blocks x 512 thr
    layer0_fused<<<256, 512, 0, stream>>>(
        W0, W1, W2, x, b0v, F1, F2, H0act, H2acc, out);

    // L1 split-K: 16 bx x 32 by x 2 kh = 1024 blocks x 256 thr (4 blocks/CU)
    layer_ks<0, 0, NT1, 32><<<1024, 256, 0, stream>>>(
        F1, x, H0act, b1v, HID, H2acc);

    // L2 split-K: 16 bx x 20 by x 2 kh -> 768-block padded grid (640 active)
    layer_ks<1, 1, NT2, 20><<<768, 256, 0, stream>>>(
        F2, x, H2acc, b2v, OUTD, out);
}

// Round 10
// 99.381 us; speedup vs baseline: 1.0130x; 1.0062x over previous
//
#include <hip/hip_runtime.h>
#include <math.h>

#define HID 512
#define IN_FEAT 342
#define OUTD 311
#define BATCH 256
#define XROW (IN_FEAT + 1)

// fragment geometry: chunk block = 1024 u16 (512 hi + 512 lo);
// element (plane, lane, j) at plane*512 + lane*8 + j; lane = q*16 + m holds
// W[s][ot*16+m][cc*32+q*8+j].
#define NT1 32
#define NCC1 16
#define NT2 20
#define NCC2 16
#define NCC0 11

typedef unsigned short u16;
typedef short bf16x8 __attribute__((ext_vector_type(8)));
typedef float f32x4 __attribute__((ext_vector_type(4)));

__device__ __forceinline__ u16 f2bf_rne(float v) {
    unsigned int x = __float_as_uint(v);
    unsigned int r = (x + 0x7fffu + ((x >> 16) & 1u)) >> 16;
    return (u16)r;
}
__device__ __forceinline__ float bf2f(u16 u) {
    return __uint_as_float(((unsigned int)u) << 16);
}

union U8 { u16 u[8]; uint4 v; };

__device__ __forceinline__ void split8(const float* __restrict__ src, bf16x8& hi, bf16x8& lo) {
#pragma unroll
    for (int j = 0; j < 8; j++) {
        u16 h = f2bf_rne(src[j]);
        hi[j] = (short)h;
        lo[j] = (short)f2bf_rne(src[j] - bf2f(h));
    }
}

// ================= L0 + prep fused (R9 structure + issue-early) =================
// Side-job F1/F2 source loads issued at kernel START into registers (T14 split);
// convert+store at kernel END -> their HBM latency hides under the whole L0 body.
// W0/H staging loops constant-trip unrolled so the compiler hoists all loads.
#define NB0 32
#define KLDS0 360
__global__ __launch_bounds__(512, 1) void layer0_fused(
    const float* __restrict__ W0, const float* __restrict__ W1, const float* __restrict__ W2,
    const float* __restrict__ x, const float* __restrict__ bias,
    u16* __restrict__ F1, u16* __restrict__ F2,
    float* __restrict__ Oact, float* __restrict__ H2acc, float* __restrict__ outz)
{
    __shared__ u16 wlds[4 * NCC0 * 1024];      // 90112 B
    __shared__ u16 hlds[2 * NB0 * KLDS0];      // 46080 B
    __shared__ float accs[4][NB0][17];         //  8704 B   (total 144.9 KB, 1 blk/CU)

    const int blk = (int)blockIdx.x;
    const int bx = (blk >> 3) & 7;
    const int by = (blk & 7) | ((blk >> 6) << 3);   // blk%8 == by%8: XCD weight locality
    const int tid = (int)threadIdx.x;
    const int b0 = bx * NB0;
    const int o0 = by * 16;

    const int lane = tid & 63;
    const int w = tid >> 6;
    const int s = w & 3;
    const int t = w >> 2;
    const int m = lane & 15;
    const int q = lane >> 4;

    // ---- dcoef x-load issued first (consumed only at blend time) ----
    const int brow = b0 + t * 16 + m;
    const float ps = 4.f * x[(size_t)brow * XROW + IN_FEAT];

    // ---- side-job source loads issued NOW, consumed at kernel end (T14) ----
    const bool sjob = (blk < 208);
    const bool w2j = sjob && (blk >= 128);
    int js = 0, jot = 0;
    u16* Fd = nullptr;
    float4 sj00 = {0,0,0,0}, sj01 = {0,0,0,0}, sj10 = {0,0,0,0}, sj11 = {0,0,0,0};
    if (sjob) {
        int l = w2j ? (blk - 128) : blk;
        if (w2j) { js = l / 20; jot = l - js * 20; }
        else     { js = l >> 5; jot = l & 31; }
        Fd = w2j ? (F2 + (size_t)(js * NT2 + jot) * NCC2 * 1024)
                 : (F1 + (size_t)(js * NT1 + jot) * NCC1 * 1024);
        {   // round 0: idx = tid (rr 0..7)
            int rr = tid >> 6, c = tid & 63;
            if (!w2j) {
                const float4* p4 = reinterpret_cast<const float4*>(
                    W1 + (size_t)(js * 512 + jot * 16 + rr) * 512 + c * 8);
                sj00 = p4[0]; sj01 = p4[1];
            } else if (jot * 16 + rr < OUTD) {
                const float4* p4 = reinterpret_cast<const float4*>(
                    W2 + ((size_t)js * OUTD + jot * 16 + rr) * 512 + c * 8);
                sj00 = p4[0]; sj01 = p4[1];
            }
        }
        {   // round 1: idx = tid + 512 (rr 8..15)
            int idx = tid + 512;
            int rr = idx >> 6, c = idx & 63;
            if (!w2j) {
                const float4* p4 = reinterpret_cast<const float4*>(
                    W1 + (size_t)(js * 512 + jot * 16 + rr) * 512 + c * 8);
                sj10 = p4[0]; sj11 = p4[1];
            } else if (jot * 16 + rr < OUTD) {
                const float4* p4 = reinterpret_cast<const float4*>(
                    W2 + ((size_t)js * OUTD + jot * 16 + rr) * 512 + c * 8);
                sj10 = p4[0]; sj11 = p4[1];
            }
        }
    }

    // ---- stage W0 fragments (4 slices) into LDS: 2816 items, 6 constant rounds ----
#pragma unroll
    for (int r6 = 0; r6 < 6; ++r6) {
        int idx = tid + r6 * 512;
        if (idx < 4 * 16 * 44) {
            int ss = idx / (16 * 44);
            int rem = idx - ss * (16 * 44);
            int rr = rem / 44, c = rem - rr * 44;
            int k = c * 8;
            const float* rp = W0 + (size_t)(ss * 512 + o0 + rr) * IN_FEAT;
            float src[8];
            if (k + 8 <= IN_FEAT) {            // rows 8B-aligned: float2 loads
                const float2* p2 = reinterpret_cast<const float2*>(rp + k);
                float2 v0 = p2[0], v1 = p2[1], v2 = p2[2], v3 = p2[3];
                src[0] = v0.x; src[1] = v0.y; src[2] = v1.x; src[3] = v1.y;
                src[4] = v2.x; src[5] = v2.y; src[6] = v3.x; src[7] = v3.y;
            } else {
#pragma unroll
                for (int j = 0; j < 8; j++) src[j] = (k + j < IN_FEAT) ? rp[k + j] : 0.f;
            }
            U8 hi, lo;
#pragma unroll
            for (int j = 0; j < 8; j++) {
                u16 h = f2bf_rne(src[j]);
                hi.u[j] = h;
                lo.u[j] = f2bf_rne(src[j] - bf2f(h));
            }
            int cc = c >> 2, fl = (c & 3) * 16 + rr;
            *reinterpret_cast<uint4*>(&wlds[(ss * NCC0 + cc) * 1024 + fl * 8])       = hi.v;
            *reinterpret_cast<uint4*>(&wlds[(ss * NCC0 + cc) * 1024 + 512 + fl * 8]) = lo.v;
        }
    }

    // ---- stage H tile from x: 1408 items, 3 constant rounds ----
#pragma unroll
    for (int r3 = 0; r3 < 3; ++r3) {
        int idx = tid + r3 * 512;
        if (idx < NB0 * 44) {
            int r = idx / 44, c = idx - r * 44;
            int k = c * 8;
            const float* xr = x + (size_t)(b0 + r) * XROW;
            float src[8];
#pragma unroll
            for (int j = 0; j < 8; j++) {
                int kk = k + j;
                src[j] = (kk < IN_FEAT) ? xr[kk] : 0.f;
            }
            bf16x8 hi, lo;
            split8(src, hi, lo);
            *reinterpret_cast<bf16x8*>(&hlds[r * KLDS0 + k])               = hi;
            *reinterpret_cast<bf16x8*>(&hlds[NB0 * KLDS0 + r * KLDS0 + k]) = lo;
        }
    }
    __syncthreads();

    const u16* wfl = &wlds[s * NCC0 * 1024 + lane * 8];
    const u16* hp  = &hlds[(t * 16 + m) * KLDS0 + q * 8];
    const u16* hpl = &hlds[NB0 * KLDS0 + (t * 16 + m) * KLDS0 + q * 8];

    const float fl2 = floorf(ps);
    const float mu = ps - fl2;
    const int i1 = ((int)fl2) & 3;
    const int jj = (s - i1) & 3;
    const float mu2 = mu * mu, mu3 = mu2 * mu;
    const float ds = (jj == 0) ? ( 1.5f * mu3 - 2.5f * mu2 + 1.0f)
                   : (jj == 1) ? (-1.5f * mu3 + 2.0f * mu2 + 0.5f * mu)
                   : (jj == 2) ? ( 0.5f * mu3 - 0.5f * mu2)
                   :             (-0.5f * mu3 + mu2 - 0.5f * mu);

    f32x4 a0 = {0.f, 0.f, 0.f, 0.f};
    f32x4 a1 = {0.f, 0.f, 0.f, 0.f};
    f32x4 a2 = {0.f, 0.f, 0.f, 0.f};
#pragma unroll
    for (int cc = 0; cc < NCC0; ++cc) {
        bf16x8 ah = *reinterpret_cast<const bf16x8*>(wfl + cc * 1024);
        bf16x8 al = *reinterpret_cast<const bf16x8*>(wfl + cc * 1024 + 512);
        bf16x8 bh = *reinterpret_cast<const bf16x8*>(hp + cc * 32);
        bf16x8 bl = *reinterpret_cast<const bf16x8*>(hpl + cc * 32);
        a0 = __builtin_amdgcn_mfma_f32_16x16x32_bf16(ah, bh, a0, 0, 0, 0);
        a1 = __builtin_amdgcn_mfma_f32_16x16x32_bf16(ah, bl, a1, 0, 0, 0);
        a2 = __builtin_amdgcn_mfma_f32_16x16x32_bf16(al, bh, a2, 0, 0, 0);
    }
    __syncthreads();

    f32x4 sum = a0 + a1 + a2;
#pragma unroll
    for (int r = 0; r < 4; ++r) {
        int o = o0 + q * 4 + r;
        accs[s][t * 16 + m][q * 4 + r] = ds * (sum[r] + bias[(size_t)s * HID + o]);
    }
    __syncthreads();

    const int b_l = tid >> 4;
    const int o_l = tid & 15;
    float vv = accs[0][b_l][o_l] + accs[1][b_l][o_l]
             + accs[2][b_l][o_l] + accs[3][b_l][o_l];
    {
        float e = (vv > 0.f) ? vv : expm1f(vv);
        Oact[(size_t)(b0 + b_l) * HID + o0 + o_l] = e;   // activated f32
    }

    // ---- side-job writeback (sources loaded at kernel start) ----
    if (sjob) {
        auto put = [&](int idx, float4 va, float4 vb) {
            float src[8] = {va.x, va.y, va.z, va.w, vb.x, vb.y, vb.z, vb.w};
            U8 hi, lo;
#pragma unroll
            for (int j = 0; j < 8; j++) {
                u16 h = f2bf_rne(src[j]);
                hi.u[j] = h;
                lo.u[j] = f2bf_rne(src[j] - bf2f(h));
            }
            int rr = idx >> 6, c = idx & 63;
            int cc = c >> 2, jl = (c & 3) * 16 + rr;
            *reinterpret_cast<uint4*>(Fd + cc * 1024 + jl * 8)       = hi.v;
            *reinterpret_cast<uint4*>(Fd + cc * 1024 + 512 + jl * 8) = lo.v;
        };
        put(tid, sj00, sj01);
        put(tid + 512, sj10, sj11);
    } else if (blk >= 208) {
        // ---- zero split-K accumulators (H2acc 131072 + out 79616 f32) ----
        for (int i = (blk - 208) * 512 + tid; i < 131072 + 79616; i += 48 * 512) {
            if (i < 131072) H2acc[i] = 0.f;
            else            outz[i - 131072] = 0.f;
        }
    }
}

// ===== L1/L2: split-K halves + depth-4 weight prefetch ring =====
// Ring: chunks 0-3 issued BEFORE H staging (latency hides under staging+barrier);
// K-step cc consumes slot cc&3 then refills it with chunk cc+4. 4 outstanding
// 1KB wave-loads/wave x 16 waves/CU ~ 64KB/CU in flight (vs ~9KB needed for peak).
#define KLDS1 264
#define KSTEP(CC, WH, WL, PF, PFCC)                                              \
    { bf16x8 bh = *reinterpret_cast<const bf16x8*>(hp + (CC) * 32);              \
      bf16x8 bl = *reinterpret_cast<const bf16x8*>(hpl + (CC) * 32);             \
      a0 = __builtin_amdgcn_mfma_f32_16x16x32_bf16(WH, bh, a0, 0, 0, 0);         \
      a1 = __builtin_amdgcn_mfma_f32_16x16x32_bf16(WH, bl, a1, 0, 0, 0);         \
      a2 = __builtin_amdgcn_mfma_f32_16x16x32_bf16(WL, bh, a2, 0, 0, 0);         \
      if (PF) { WH = *reinterpret_cast<const bf16x8*>(wf + (PFCC) * 1024);       \
                WL = *reinterpret_cast<const bf16x8*>(wf + (PFCC) * 1024 + 512); } }

template<int FINAL, int ACT, int NT, int NBY>
__global__ __launch_bounds__(256, 4) void layer_ks(
    const u16* __restrict__ Wf, const float* __restrict__ x,
    const float* __restrict__ Hin, const float* __restrict__ bias, int Mb,
    float* __restrict__ accout)
{
    union SharedU {
        u16 h[2][16 * KLDS1];
        float acc[4][16][17];
    };
    __shared__ SharedU sm;

    const int blk = (int)blockIdx.x;
    const int bx = (blk >> 3) & 15;
    const int kh = (blk >> 7) & 1;
    const int by = (blk & 7) | ((blk >> 8) << 3);
    if (by >= NBY) return;

    const int tid = (int)threadIdx.x;
    const int b0 = bx * 16;
    const int o0 = by * 16;
    const int lane = tid & 63;
    const int s = tid >> 6;                   // wave = slice
    const int m = lane & 15;
    const int q = lane >> 4;

    // ---- dcoef x-load issued first ----
    const int brow = b0 + m;
    const float ps = 4.f * x[(size_t)brow * XROW + IN_FEAT];

    // ---- weight ring: issue chunks 0..3 before H staging ----
    const u16* wf = Wf + ((size_t)(s * NT + by) * 16 + kh * 8) * 1024 + lane * 8;
    bf16x8 wh0 = *reinterpret_cast<const bf16x8*>(wf);
    bf16x8 wl0 = *reinterpret_cast<const bf16x8*>(wf + 512);
    bf16x8 wh1 = *reinterpret_cast<const bf16x8*>(wf + 1024);
    bf16x8 wl1 = *reinterpret_cast<const bf16x8*>(wf + 1024 + 512);
    bf16x8 wh2 = *reinterpret_cast<const bf16x8*>(wf + 2048);
    bf16x8 wl2 = *reinterpret_cast<const bf16x8*>(wf + 2048 + 512);
    bf16x8 wh3 = *reinterpret_cast<const bf16x8*>(wf + 3072);
    bf16x8 wl3 = *reinterpret_cast<const bf16x8*>(wf + 3072 + 512);

    // ---- stage H half-tile (16 x 256 f32): 2 constant rounds ----
#pragma unroll
    for (int r2 = 0; r2 < 2; ++r2) {
        int idx = tid + r2 * 256;
        int r = idx >> 5, c = idx & 31;
        const float4* hv = reinterpret_cast<const float4*>(
            Hin + (size_t)(b0 + r) * HID + kh * 256 + c * 8);
        float4 v0 = hv[0], v1 = hv[1];
        float src[8] = {v0.x, v0.y, v0.z, v0.w, v1.x, v1.y, v1.z, v1.w};
        if (ACT) {
#pragma unroll
            for (int j = 0; j < 8; j++) src[j] = (src[j] > 0.f) ? src[j] : expm1f(src[j]);
        }
        bf16x8 hi, lo;
        split8(src, hi, lo);
        *reinterpret_cast<bf16x8*>(&sm.h[0][r * KLDS1 + c * 8]) = hi;
        *reinterpret_cast<bf16x8*>(&sm.h[1][r * KLDS1 + c * 8]) = lo;
    }
    __syncthreads();

    const u16* hp  = &sm.h[0][m * KLDS1 + q * 8];
    const u16* hpl = &sm.h[1][m * KLDS1 + q * 8];

    const float fl = floorf(ps);
    const float mu = ps - fl;
    const int i1 = ((int)fl) & 3;
    const int jj = (s - i1) & 3;
    const float mu2 = mu * mu, mu3 = mu2 * mu;
    const float ds = (jj == 0) ? ( 1.5f * mu3 - 2.5f * mu2 + 1.0f)
                   : (jj == 1) ? (-1.5f * mu3 + 2.0f * mu2 + 0.5f * mu)
                   : (jj == 2) ? ( 0.5f * mu3 - 0.5f * mu2)
                   :             (-0.5f * mu3 + mu2 - 0.5f * mu);

    f32x4 a0 = {0.f, 0.f, 0.f, 0.f};
    f32x4 a1 = {0.f, 0.f, 0.f, 0.f};
    f32x4 a2 = {0.f, 0.f, 0.f, 0.f};
    KSTEP(0, wh0, wl0, 1, 4)
    KSTEP(1, wh1, wl1, 1, 5)
    KSTEP(2, wh2, wl2, 1, 6)
    KSTEP(3, wh3, wl3, 1, 7)
    KSTEP(4, wh0, wl0, 0, 0)
    KSTEP(5, wh1, wl1, 0, 0)
    KSTEP(6, wh2, wl2, 0, 0)
    KSTEP(7, wh3, wl3, 0, 0)
    __syncthreads();

    f32x4 sum = a0 + a1 + a2;
#pragma unroll
    for (int r = 0; r < 4; ++r) {
        int o = o0 + q * 4 + r;
        float bb = (kh == 0 && o < Mb) ? bias[(size_t)s * Mb + o] : 0.f;
        sm.acc[s][m][q * 4 + r] = ds * (sum[r] + bb);
    }
    __syncthreads();

    const int b_l = tid >> 4;
    const int o_l = tid & 15;
    float vv = sm.acc[0][b_l][o_l] + sm.acc[1][b_l][o_l]
             + sm.acc[2][b_l][o_l] + sm.acc[3][b_l][o_l];
    const int o = o0 + o_l;
    const int b = b0 + b_l;
    if (FINAL) {
        if (o < OUTD) unsafeAtomicAdd(&accout[(size_t)b * OUTD + o], vv);
    } else {
        unsafeAtomicAdd(&accout[(size_t)b * HID + o], vv);
    }
}

extern "C" void kernel_launch(void* const* d_in, const int* in_sizes, int n_in,
                              void* d_out, int out_size, void* d_ws, size_t ws_size,
                              hipStream_t stream) {
    const float* x  = (const float*)d_in[0];
    const float* W0 = (const float*)d_in[1];
    const float* b0v = (const float*)d_in[2];
    const float* W1 = (const float*)d_in[3];
    const float* b1v = (const float*)d_in[4];
    const float* W2 = (const float*)d_in[5];
    const float* b2v = (const float*)d_in[6];
    float* out = (float*)d_out;

    char* pw = (char*)d_ws;
    auto alloc = [&](size_t bytes) { char* r = pw; pw += (bytes + 255) & ~(size_t)255; return r; };

    u16* F1 = (u16*)alloc((size_t)4 * NT1 * NCC1 * 1024 * 2);
    u16* F2 = (u16*)alloc((size_t)4 * NT2 * NCC2 * 1024 * 2);
    float* H0act = (float*)alloc((size_t)BATCH * HID * 4);
    float* H2acc = (float*)alloc((size_t)BATCH * HID * 4);

    // L0 (+ F1/F2 prep via T14 issue-early/write-late + accumulator zeroing)
    layer0_fused<<<256, 512, 0, stream>>>(
        W0, W1, W2, x, b0v, F1, F2, H0act, H2acc, out);

    // L1 split-K: 16 bx x 32 by x 2 kh = 1024 blocks x 256 thr (4 blocks/CU)
    layer_ks<0, 0, NT1, 32><<<1024, 256, 0, stream>>>(
        F1, x, H0act, b1v, HID, H2acc);

    // L2 split-K: 16 bx x 20 by x 2 kh -> 768-block padded grid (640 active)
    layer_ks<1, 1, NT2, 20><<<768, 256, 0, stream>>>(
        F2, x, H2acc, b2v, OUTD, out);
}